// Round 1
// baseline (434.121 us; speedup 1.0000x reference)
//
#include <hip/hip_runtime.h>
#include <math.h>

// (T,B,C,H,W) = (9,8,256,56,56), fp32.
// Persistent-pipeline fused kernel. 512 blocks (exactly 2/CU at 76 KB LDS),
// each owns 6-7 chunks of 8 pixels. Next chunk is prefetched into REGISTERS
// (18x float4) before the compute phases; all in-loop barriers are raw
// s_barrier + lgkmcnt(0) only, so vmcnt is NEVER drained mid-loop and the
// prefetch stays in flight across scores/softmax/attend (HBM never idles).
// Tile is stored with an XOR swizzle on word bits 2-4 (f = (c>>2)&7), a pure
// bijection applied at every access:
//   - scores (c = cp+4i interleave): bank = (8cp+px)%32 -> 32 distinct, free
//   - attend b128 rows: bank-groups (2c ^ f)%8 -> uniform over all 8 groups
//   - stage ds_write: 8 consecutive blocks XOR const -> still conflict-free
// Math note (validated previous session, absmax 7.8e-3): score_center and
// bias are constant along softmax axis t -> shift-invariant -> dropped.
#define TT 9
#define BN 8
#define CC 256
#define HW 3136
#define P 8
#define NCHUNK (HW / P)       // 392
#define ITEMS (BN * NCHUNK)   // 3136
#define GRID 512              // 2 blocks/CU on 256 CUs
#define CENTER_T 4

// Raw barrier: waits this wave's LDS ops, syncs, drains NOTHING else.
// asm "memory" clobber = IR-level fence; sched_barrier(0) = MIR-level fence.
#define BAR_LGKM()                                        \
  do {                                                    \
    __builtin_amdgcn_sched_barrier(0);                    \
    asm volatile("s_waitcnt lgkmcnt(0)" ::: "memory");    \
    __builtin_amdgcn_s_barrier();                         \
    __builtin_amdgcn_sched_barrier(0);                    \
  } while (0)

__global__ __launch_bounds__(256, 2) void fused_pipe_kernel(
    const float* __restrict__ seq, const float* __restrict__ w,
    const float* __restrict__ gamma, float* __restrict__ out) {
  const int bid = blockIdx.x;
  const int b = bid & 7;         // XCD affinity: batch b lives on XCD b
  const int tid = threadIdx.x;

  __shared__ __align__(16) float tile[TT * CC * P];  // 73728 B, swizzled
  __shared__ float wsh[CC];
  __shared__ float red[TT * P * 4];                  // 288 partials
  __shared__ __align__(16) float sc[TT * P];         // attn weights

  wsh[tid] = w[CC + tid];  // w_other
  const float gm = gamma[0];

  // Stage mapping: k in [0,18): t = k>>1, c = (k&1)*128 + (tid>>1), g = (tid&1)*4
  const int c_lo = tid >> 1;
  const int g = (tid & 1) * 4;
  const int fsw = ((c_lo >> 2) & 7) << 2;        // swizzle bits (same for both k-halves)
  const int wbase = (8 * c_lo + g) ^ fsw;        // + t*2048 + (k&1)*1024
  const float* sgb = seq + (size_t)b * CC * HW + (size_t)c_lo * HW + g;

  int px0 = (bid >> 3) * P;                      // chunk = bid>>3 + 64*it
  const int nit = (bid < (ITEMS % GRID)) ? (ITEMS / GRID + 1) : (ITEMS / GRID);

  float4 pre[18];
  // ---- prologue prefetch (chunk 0 for this block) ----
#pragma unroll
  for (int k = 0; k < 18; ++k) {
    const int koff = (k >> 1) * (BN * CC * HW) + (k & 1) * (128 * HW);
    pre[k] = *(const float4*)(sgb + koff + px0);
  }

  for (int it = 0; it < nit; ++it) {
    // ---- commit prefetched tile to LDS (swizzled); vmcnt waited here ----
#pragma unroll
    for (int k = 0; k < 18; ++k) {
      *(float4*)(&tile[wbase + (k >> 1) * 2048 + (k & 1) * 1024]) = pre[k];
    }
    // ---- issue next prefetch NOW; stays in flight across all barriers ----
    if (it + 1 < nit) {
      const int px0n = px0 + (GRID / BN) * P;  // +512 pixels
#pragma unroll
      for (int k = 0; k < 18; ++k) {
        const int koff = (k >> 1) * (BN * CC * HW) + (k & 1) * (128 * HW);
        pre[k] = *(const float4*)(sgb + koff + px0n);
      }
    }
    BAR_LGKM();  // tile visible to all waves

    // ---- scores: 288 items = 72 (t,px) pairs x 4 interleaved c-partitions ----
    {
      const int pair = tid >> 2, cp = tid & 3;
      const int t = pair >> 3, px = pair & 7;
      const int sbase = (t * CC + cp) * P + px;  // bits 2-4 free of t-term
      float a = 0.f;
#pragma unroll
      for (int i = 0; i < 64; ++i)
        a = fmaf(tile[(sbase ^ ((i & 7) << 2)) + 32 * i], wsh[cp + 4 * i], a);
      red[tid] = a;
      if (tid < 32) {  // t = 8 remainder, wave 0 only
        const int cp2 = tid & 3;
        const int px2 = ((tid + 256) >> 2) & 7;
        const int sbase2 = (8 * CC + cp2) * P + px2;
        float a2 = 0.f;
#pragma unroll
        for (int i = 0; i < 64; ++i)
          a2 = fmaf(tile[(sbase2 ^ ((i & 7) << 2)) + 32 * i], wsh[cp2 + 4 * i], a2);
        red[tid + 256] = a2;
      }
    }
    BAR_LGKM();

    // ---- reduce partials + softmax over t (one thread per pixel) ----
    if (tid < P) {
      float vv[TT];
      float m = -1e30f;
#pragma unroll
      for (int t = 0; t < TT; ++t) {
        const int pr = (t * P + tid) * 4;
        const float s = red[pr] + red[pr + 1] + red[pr + 2] + red[pr + 3];
        vv[t] = s;
        m = fmaxf(m, s);
      }
      float s = 0.f;
#pragma unroll
      for (int t = 0; t < TT; ++t) { vv[t] = __expf(vv[t] - m); s += vv[t]; }
      const float inv = 1.f / s;
#pragma unroll
      for (int t = 0; t < TT; ++t) sc[t * P + tid] = vv[t] * inv;
    }
    BAR_LGKM();

    // ---- attend: thread = channel, swizzled b128 rows, sc reads broadcast ----
    {
      const int c = tid;
      const int f2 = ((c >> 2) & 7) << 2;
      const int abase0 = (8 * c) ^ f2;       // + t*2048
      const int abase4 = (8 * c + 4) ^ f2;   // + t*2048
      float4 o0 = {0.f, 0.f, 0.f, 0.f}, o1 = {0.f, 0.f, 0.f, 0.f};
      float4 c0v = {0.f, 0.f, 0.f, 0.f}, c1v = {0.f, 0.f, 0.f, 0.f};
#pragma unroll
      for (int t = 0; t < TT; ++t) {
        const float4 s0 = *(const float4*)(&sc[t * P]);
        const float4 s1 = *(const float4*)(&sc[t * P + 4]);
        const float4 v0 = *(const float4*)(&tile[abase0 + t * 2048]);
        const float4 v1 = *(const float4*)(&tile[abase4 + t * 2048]);
        o0.x = fmaf(s0.x, v0.x, o0.x);
        o0.y = fmaf(s0.y, v0.y, o0.y);
        o0.z = fmaf(s0.z, v0.z, o0.z);
        o0.w = fmaf(s0.w, v0.w, o0.w);
        o1.x = fmaf(s1.x, v1.x, o1.x);
        o1.y = fmaf(s1.y, v1.y, o1.y);
        o1.z = fmaf(s1.z, v1.z, o1.z);
        o1.w = fmaf(s1.w, v1.w, o1.w);
        if (t == CENTER_T) { c0v = v0; c1v = v1; }
      }
      float4 r0, r1;
      r0.x = fmaf(gm, o0.x, c0v.x);
      r0.y = fmaf(gm, o0.y, c0v.y);
      r0.z = fmaf(gm, o0.z, c0v.z);
      r0.w = fmaf(gm, o0.w, c0v.w);
      r1.x = fmaf(gm, o1.x, c1v.x);
      r1.y = fmaf(gm, o1.y, c1v.y);
      r1.z = fmaf(gm, o1.z, c1v.z);
      r1.w = fmaf(gm, o1.w, c1v.w);
      float* ob = out + ((size_t)b * CC + c) * HW + px0;
      *(float4*)(ob) = r0;
      *(float4*)(ob + 4) = r1;
    }

    px0 += (GRID / BN) * P;  // next chunk (+64 chunks = +512 px)
    BAR_LGKM();              // all tile reads done before next ds_write
  }
}

extern "C" void kernel_launch(void* const* d_in, const int* in_sizes, int n_in,
                              void* d_out, int out_size, void* d_ws, size_t ws_size,
                              hipStream_t stream) {
  const float* seq = (const float*)d_in[0];
  const float* w = (const float*)d_in[1];
  // d_in[2] (bias) unused: softmax shift-invariant.
  const float* gamma = (const float*)d_in[3];
  float* out = (float*)d_out;

  fused_pipe_kernel<<<GRID, 256, 0, stream>>>(seq, w, gamma, out);
}

// Round 2
// 344.331 us; speedup vs baseline: 1.2608x; 1.2608x over previous
//
#include <hip/hip_runtime.h>
#include <math.h>

// (T,B,C,H,W) = (9,8,256,56,56), fp32.
// Round-0 structure (3136 single-chunk blocks, proven ~66us kernel) + the
// two LDS conflict fixes validated in round 1:
//  - tile stored with XOR swizzle on word bits 2-4, f(c) = ((c>>2)&7)<<2.
//    Pure bijection within each 8-word row; applied identically at stage
//    write, scores read, attend read.
//  - scores use c-interleave c = cp + 4*i: bank = (8cp+px)^const -> all 32
//    banks distinct, 2 lanes/bank (free), vs 8-way conflict before.
//  - attend b128 rows: groups (2c)^f cover all 8 bank groups uniformly
//    (round 0 hit only even groups -> 2x serialization on that phase).
// Cross-block overlap does the HBM latency hiding (blocks at staggered
// phases); round 1 proved the persistent/lockstep variant is 3x WORSE.
// Math note (validated, absmax <= 1.6e-2): score_center and bias are
// constant along softmax axis t -> shift-invariant -> dropped.
#define TT 9
#define BN 8
#define CC 256
#define HW 3136
#define P 8               // pixels per block
#define NCHUNK (HW / P)   // 392
#define CENTER_T 4

__global__ __launch_bounds__(256) void fused_stage_kernel(
    const float* __restrict__ seq, const float* __restrict__ w,
    const float* __restrict__ gamma, float* __restrict__ out) {
  // blk%8 -> batch b; consecutive chunks land 8 bids apart -> same XCD,
  // co-resident -> L2 merges both the 32B read segments and the 32B write
  // segments of neighboring chunks into full lines.
  int blk = blockIdx.x;
  int b = blk & 7;
  int chunk = blk >> 3;    // 0..391
  int px0 = chunk * P;
  int tid = threadIdx.x;

  __shared__ __align__(16) float tile[TT * CC * P];  // 73728 B, swizzled
  __shared__ float wsh[CC];
  __shared__ float red[TT * P * 4];                  // 288 partials
  __shared__ __align__(16) float sc[TT * P];         // attn weights

  wsh[tid] = w[CC + tid];  // w_other

  // ---- Stage: 4608 float4 = 18 per thread; swizzled LDS writes ----
  {
    const int c_lo = tid >> 1;           // 0..127
    const int g = (tid & 1) * 4;         // 0 or 4
    const int fsw = ((c_lo >> 2) & 7) << 2;
    const int wbase = (8 * c_lo + g) ^ fsw;  // + t*2048 + (k&1)*1024
    const float* sgb = seq + (size_t)b * CC * HW + (size_t)c_lo * HW + g + px0;
#pragma unroll
    for (int k = 0; k < 18; ++k) {
      const int koff = (k >> 1) * (BN * CC * HW) + (k & 1) * (128 * HW);
      float4 v = *(const float4*)(sgb + koff);
      *(float4*)(&tile[wbase + (k >> 1) * 2048 + (k & 1) * 1024]) = v;
    }
  }
  __syncthreads();

  // ---- Scores: 288 items = 72 (t,px) pairs x 4 interleaved c-partitions.
  // c = cp + 4*i: bank = (8cp+px) ^ ((i&7)<<2) -> 32 distinct, 2-way (free).
  for (int v = tid; v < 288; v += 256) {
    const int pair = v >> 2;   // t*8 + px
    const int cp = v & 3;
    const int t = pair >> 3;
    const int px = pair & 7;
    const int sbase = t * 2048 + cp * 8 + px;
    float a = 0.f;
#pragma unroll
    for (int i = 0; i < 64; ++i)
      a = fmaf(tile[(sbase ^ ((i & 7) << 2)) + 32 * i], wsh[cp + 4 * i], a);
    red[v] = a;
  }
  __syncthreads();

  // ---- Reduce partials + softmax over t (one thread per pixel) ----
  if (tid < P) {
    float vv[TT];
    float m = -1e30f;
#pragma unroll
    for (int t = 0; t < TT; ++t) {
      const int pr = (t * P + tid) * 4;
      const float s = red[pr] + red[pr + 1] + red[pr + 2] + red[pr + 3];
      vv[t] = s;
      m = fmaxf(m, s);
    }
    float s = 0.f;
#pragma unroll
    for (int t = 0; t < TT; ++t) { vv[t] = __expf(vv[t] - m); s += vv[t]; }
    const float inv = 1.f / s;
#pragma unroll
    for (int t = 0; t < TT; ++t) sc[t * P + tid] = vv[t] * inv;
  }
  __syncthreads();

  // ---- Attend: thread = channel; swizzled b128 rows hit all 8 bank groups
  // uniformly; sc reads are broadcasts.
  {
    const int c = tid;
    const int f2 = ((c >> 2) & 7) << 2;
    const int abase0 = (8 * c) ^ f2;       // + t*2048
    const int abase4 = (8 * c + 4) ^ f2;   // + t*2048
    float4 o0 = {0.f, 0.f, 0.f, 0.f}, o1 = {0.f, 0.f, 0.f, 0.f};
    float4 c0v = {0.f, 0.f, 0.f, 0.f}, c1v = {0.f, 0.f, 0.f, 0.f};
#pragma unroll
    for (int t = 0; t < TT; ++t) {
      const float4 s0 = *(const float4*)(&sc[t * P]);
      const float4 s1 = *(const float4*)(&sc[t * P + 4]);
      const float4 v0 = *(const float4*)(&tile[abase0 + t * 2048]);
      const float4 v1 = *(const float4*)(&tile[abase4 + t * 2048]);
      o0.x = fmaf(s0.x, v0.x, o0.x);
      o0.y = fmaf(s0.y, v0.y, o0.y);
      o0.z = fmaf(s0.z, v0.z, o0.z);
      o0.w = fmaf(s0.w, v0.w, o0.w);
      o1.x = fmaf(s1.x, v1.x, o1.x);
      o1.y = fmaf(s1.y, v1.y, o1.y);
      o1.z = fmaf(s1.z, v1.z, o1.z);
      o1.w = fmaf(s1.w, v1.w, o1.w);
      if (t == CENTER_T) { c0v = v0; c1v = v1; }
    }
    const float gm = gamma[0];
    float4 r0, r1;
    r0.x = fmaf(gm, o0.x, c0v.x);
    r0.y = fmaf(gm, o0.y, c0v.y);
    r0.z = fmaf(gm, o0.z, c0v.z);
    r0.w = fmaf(gm, o0.w, c0v.w);
    r1.x = fmaf(gm, o1.x, c1v.x);
    r1.y = fmaf(gm, o1.y, c1v.y);
    r1.z = fmaf(gm, o1.z, c1v.z);
    r1.w = fmaf(gm, o1.w, c1v.w);
    float* ob = out + ((size_t)b * CC + c) * HW + px0;
    *(float4*)(ob) = r0;
    *(float4*)(ob + 4) = r1;
  }
}

extern "C" void kernel_launch(void* const* d_in, const int* in_sizes, int n_in,
                              void* d_out, int out_size, void* d_ws, size_t ws_size,
                              hipStream_t stream) {
  const float* seq = (const float*)d_in[0];
  const float* w = (const float*)d_in[1];
  // d_in[2] (bias) unused: softmax shift-invariant.
  const float* gamma = (const float*)d_in[3];
  float* out = (float*)d_out;

  fused_stage_kernel<<<BN * NCHUNK, 256, 0, stream>>>(seq, w, gamma, out);
}